// Round 4
// baseline (2029.606 us; speedup 1.0000x reference)
//
#include <hip/hip_runtime.h>
#include <hip/hip_bf16.h>
#include <math.h>

// ---------------------------------------------------------------------------
// Types
// ---------------------------------------------------------------------------
typedef __bf16 bf16_t;
typedef __bf16 bf16x8 __attribute__((ext_vector_type(8)));
typedef __bf16 bf16x4 __attribute__((ext_vector_type(4)));
typedef float  f32x4  __attribute__((ext_vector_type(4)));

#define MFMA_BF16(a, b, c) __builtin_amdgcn_mfma_f32_16x16x32_bf16((a), (b), (c), 0, 0, 0)

typedef const void __attribute__((address_space(1)))* gas_ptr;
typedef void       __attribute__((address_space(3)))* las_ptr;

__device__ __forceinline__ void gload_lds16(const void* g, void* l) {
  // global -> LDS direct, 16B per lane. LDS dest is wave-uniform base + lane*16.
  __builtin_amdgcn_global_load_lds((gas_ptr)g, (las_ptr)l, 16, 0, 0);
}

// ---------------------------------------------------------------------------
// Model constants
// ---------------------------------------------------------------------------
static constexpr int B_ = 4, S_ = 1024, D_ = 1024, HF_ = 4096, V_ = 32000;
static constexpr int NH_ = 16, HD_ = 64;
static constexpr int TOK_ = B_ * S_;  // 4096

// ---------------------------------------------------------------------------
// fp32 -> bf16 conversion (vectorized x4)
// ---------------------------------------------------------------------------
__global__ __launch_bounds__(256) void cvt_f32_bf16(const float* __restrict__ in,
                                                    bf16_t* __restrict__ out, int n4) {
  int i = blockIdx.x * 256 + threadIdx.x;
  if (i < n4) {
    float4 v = ((const float4*)in)[i];
    bf16x4 o;
    o[0] = (bf16_t)v.x; o[1] = (bf16_t)v.y; o[2] = (bf16_t)v.z; o[3] = (bf16_t)v.w;
    ((bf16x4*)out)[i] = o;
  }
}

// ---------------------------------------------------------------------------
// Sinusoidal positional encoding table
// ---------------------------------------------------------------------------
__global__ __launch_bounds__(256) void pe_kernel(float* __restrict__ pe) {
  const int s = blockIdx.x;
  for (int i = threadIdx.x; i < D_ / 2; i += 256) {
    float div = expf((2.0f * (float)i) * (-9.210340371976184f / (float)D_)); // ln(10000)
    float a = (float)s * div;
    pe[(size_t)s * D_ + 2 * i]     = sinf(a);
    pe[(size_t)s * D_ + 2 * i + 1] = cosf(a);
  }
}

// ---------------------------------------------------------------------------
// Embedding: h[t][d] = emb_W[x[t]][d] * 32 + pe[t % S][d]
// ---------------------------------------------------------------------------
__global__ __launch_bounds__(256) void embed_kernel(const int* __restrict__ x,
                                                    const float* __restrict__ embW,
                                                    const float* __restrict__ pe,
                                                    float* __restrict__ h) {
  int i = blockIdx.x * 256 + threadIdx.x;
  int token = i >> 8;
  int c4 = i & 255;
  int idx = x[token];
  float4 e = ((const float4*)(embW + (size_t)idx * D_))[c4];
  float4 p = ((const float4*)(pe + (size_t)(token & (S_ - 1)) * D_))[c4];
  float4 o;
  o.x = e.x * 32.0f + p.x; o.y = e.y * 32.0f + p.y;
  o.z = e.z * 32.0f + p.z; o.w = e.w * 32.0f + p.w;
  ((float4*)(h + (size_t)token * D_))[c4] = o;
}

// ---------------------------------------------------------------------------
// a_in = h + LayerNorm(h)*g + b   -> bf16
// ---------------------------------------------------------------------------
__global__ __launch_bounds__(256) void ln_res_kernel(const float* __restrict__ h,
                                                     const float* __restrict__ gamma,
                                                     const float* __restrict__ beta,
                                                     bf16_t* __restrict__ out) {
  const int row = blockIdx.x;
  const int tid = threadIdx.x;
  const float4 v = ((const float4*)(h + (size_t)row * D_))[tid];
  float s  = v.x + v.y + v.z + v.w;
  float s2 = v.x * v.x + v.y * v.y + v.z * v.z + v.w * v.w;
#pragma unroll
  for (int m = 1; m < 64; m <<= 1) {
    s  += __shfl_xor(s, m, 64);
    s2 += __shfl_xor(s2, m, 64);
  }
  __shared__ float red[2][4];
  const int wave = tid >> 6, lane = tid & 63;
  if (lane == 0) { red[0][wave] = s; red[1][wave] = s2; }
  __syncthreads();
  s  = red[0][0] + red[0][1] + red[0][2] + red[0][3];
  s2 = red[1][0] + red[1][1] + red[1][2] + red[1][3];
  const float mu   = s * (1.0f / D_);
  const float rstd = rsqrtf(s2 * (1.0f / D_) - mu * mu + 1e-5f);
  const float4 g4 = ((const float4*)gamma)[tid];
  const float4 b4 = ((const float4*)beta)[tid];
  bf16x4 o;
  o[0] = (bf16_t)(v.x + (v.x - mu) * rstd * g4.x + b4.x);
  o[1] = (bf16_t)(v.y + (v.y - mu) * rstd * g4.y + b4.y);
  o[2] = (bf16_t)(v.z + (v.z - mu) * rstd * g4.z + b4.z);
  o[3] = (bf16_t)(v.w + (v.w - mu) * rstd * g4.w + b4.w);
  ((bf16x4*)(out + (size_t)row * D_))[tid] = o;
}

// ---------------------------------------------------------------------------
// 8-phase pipelined GEMM (m201 port): C[4096,N] = A[4096,K] @ W[N,K]^T.
// BM=BN=256, BK=64, 8 waves (2M x 4N), 2 LDS double-buffers (128 KB),
// 4 phases per K-tile: {ds_read subtile | stage -> barrier -> lgkmcnt(0) ->
// setprio(1) 16 MFMA setprio(0) -> barrier}. vmcnt(0) only once per K-tile,
// after P3's MFMA (drain overlaps ~3 phases of compute).
// Swizzle: col ^= (row&7)<<4 within 128-B rows, applied as involution
// (inverse-swizzled global source, linear gload_lds dest, swizzled ds_read).
// M-fastest block order + XCD swizzle. K multiple of 64; M = 4096 fixed.
// Epilogues: 0 QKV-scatter, 2 bias+relu->bf16 (nt), 4 bias->f32 (nt).
// ---------------------------------------------------------------------------
template <int EPI>
__global__ __launch_bounds__(512, 2) void gemm_pipe(
    const bf16_t* __restrict__ A, const bf16_t* __restrict__ W, int N, int K,
    float* __restrict__ fout, const float* __restrict__ bias, bf16_t* __restrict__ bout,
    bf16_t* __restrict__ qb, bf16_t* __restrict__ kb, bf16_t* __restrict__ vtb) {
  __shared__ char ldsbuf[2][65536];  // per buf: A 32 KB (256r x 128B) + B 32 KB

  const int tid = threadIdx.x;
  const int wave = tid >> 6, lane = tid & 63;
  const int row16 = lane & 15, kgrp = lane >> 4;
  const int wm = wave >> 2, wn = wave & 3;  // 2 x 4 wave grid

  // block swizzle: XCD-bijective (grid % 8 == 0), then M-fastest (16 M-tiles)
  const int nb = gridDim.x;
  const int logical = (blockIdx.x & 7) * (nb >> 3) + (blockIdx.x >> 3);
  const int m0 = (logical & 15) << 8;
  const int n0 = (logical >> 4) << 8;

  // staging: lane covers row (..+lrow), 16 B at inverse-swizzled byte col
  const int lrow = lane >> 3;
  const int sw = ((lane & 7) * 16) ^ (lrow << 4);
  const size_t K2 = (size_t)K * 2;
  const char* gA = (const char*)A + (size_t)(m0 + wave * 8 + lrow) * K2 + sw;
  const char* gB = (const char*)W + (size_t)(n0 + wave * 8 + lrow) * K2 + sw;
  char* const ldsc = &ldsbuf[0][0];
  char* const stA = ldsc + wave * 1024;
  char* const stB = ldsc + 32768 + wave * 1024;

#define STAGE_A(tt)                                   \
  {                                                   \
    char* d_ = stA + (((tt) & 1) << 16);              \
    const char* g_ = gA + (size_t)(tt) * 128;         \
    gload_lds16(g_, d_);                              \
    gload_lds16(g_ + 64 * K2, d_ + 8192);             \
    gload_lds16(g_ + 128 * K2, d_ + 16384);           \
    gload_lds16(g_ + 192 * K2, d_ + 24576);           \
  }
#define STAGE_B(tt)                                   \
  {                                                   \
    char* d_ = stB + (((tt) & 1) << 16);              \
    const char* g_ = gB + (size_t)(tt) * 128;         \
    gload_lds16(g_, d_);                              \
    gload_lds16(g_ + 64 * K2, d_ + 8192);             \
    gload_lds16(g_ + 128 * K2, d_ + 16384);           \
    gload_lds16(g_ + 192 * K2, d_ + 24576);           \
  }

  // swizzled ds_read base offsets (bytes)
  const int colx0 = (kgrp * 16) ^ ((row16 & 7) << 4);
  const int colx1 = (64 + kgrp * 16) ^ ((row16 & 7) << 4);
  const int aB0 = (wm * 128 + row16) * 128 + colx0;
  const int aB1 = (wm * 128 + row16) * 128 + colx1;
  const int bB0 = 32768 + (wn * 64 + row16) * 128 + colx0;
  const int bB1 = 32768 + (wn * 64 + row16) * 128 + colx1;

#define LOAD_A(AF, MOFF)                                                   \
  _Pragma("unroll") for (int m_ = 0; m_ < 4; m_++) {                       \
    AF[m_][0] = *(const bf16x8*)(bufp + aB0 + (MOFF) + m_ * 2048);         \
    AF[m_][1] = *(const bf16x8*)(bufp + aB1 + (MOFF) + m_ * 2048);         \
  }
#define LOAD_B(BF, NOFF)                                                   \
  _Pragma("unroll") for (int n_ = 0; n_ < 2; n_++) {                       \
    BF[n_][0] = *(const bf16x8*)(bufp + bB0 + (NOFF) + n_ * 2048);         \
    BF[n_][1] = *(const bf16x8*)(bufp + bB1 + (NOFF) + n_ * 2048);         \
  }
#define PHASE_GATE()                                   \
  __builtin_amdgcn_s_barrier();                        \
  asm volatile("s_waitcnt lgkmcnt(0)" ::: "memory");   \
  __builtin_amdgcn_sched_barrier(0);
#define PHASE_MFMA(MB, NB, AF, BF)                                             \
  __builtin_amdgcn_s_setprio(1);                                               \
  _Pragma("unroll") for (int kh_ = 0; kh_ < 2; kh_++) {                        \
    _Pragma("unroll") for (int m_ = 0; m_ < 4; m_++) {                         \
      _Pragma("unroll") for (int n_ = 0; n_ < 2; n_++)                         \
          acc[(MB) + m_][(NB) + n_] =                                          \
              MFMA_BF16(AF[m_][kh_], BF[n_][kh_], acc[(MB) + m_][(NB) + n_]);  \
    }                                                                          \
  }                                                                            \
  __builtin_amdgcn_s_setprio(0);

  f32x4 acc[8][4] = {};
  bf16x8 af[4][2], bfA[2][2], bfB[2][2];
  const int NT = K >> 6;  // K-tiles of 64

  STAGE_A(0);
  STAGE_B(0);
  asm volatile("s_waitcnt vmcnt(0)" ::: "memory");
  __builtin_amdgcn_s_barrier();

  for (int t = 0; t < NT; ++t) {
    const char* bufp = ldsc + ((t & 1) << 16);
    const bool pf = (t + 1 < NT);
    // ---- P0: quadrant m0-3 x n0-1 ----
    LOAD_A(af, 0);
    LOAD_B(bfA, 0);
    if (pf) STAGE_A(t + 1);
    PHASE_GATE();
    PHASE_MFMA(0, 0, af, bfA);
    __builtin_amdgcn_s_barrier();
    // ---- P1: quadrant m0-3 x n2-3 ----
    LOAD_B(bfB, 4096);
    if (pf) STAGE_B(t + 1);
    PHASE_GATE();
    PHASE_MFMA(0, 2, af, bfB);
    __builtin_amdgcn_s_barrier();
    // ---- P2: quadrant m4-7 x n2-3 ----
    LOAD_A(af, 8192);
    PHASE_GATE();
    PHASE_MFMA(4, 2, af, bfB);
    __builtin_amdgcn_s_barrier();
    // ---- P3: quadrant m4-7 x n0-1 ----
    LOAD_B(bfA, 0);
    PHASE_GATE();
    PHASE_MFMA(4, 0, af, bfA);
    if (pf) asm volatile("s_waitcnt vmcnt(0)" ::: "memory");  // t+1 staged
    __builtin_amdgcn_s_barrier();
  }
#undef STAGE_A
#undef STAGE_B
#undef LOAD_A
#undef LOAD_B
#undef PHASE_GATE
#undef PHASE_MFMA

  // epilogue: C row = m0+wm*128+m*16+kgrp*4+r, col = n0+wn*64+n*16+row16
#pragma unroll
  for (int m = 0; m < 8; m++) {
    const int rowb = m0 + wm * 128 + m * 16 + kgrp * 4;
#pragma unroll
    for (int n = 0; n < 4; n++) {
      const int col = n0 + wn * 64 + n * 16 + row16;
#pragma unroll
      for (int r = 0; r < 4; r++) {
        const float v = acc[m][n][r];
        const int rr2 = rowb + r;
        if constexpr (EPI == 0) {
          const int bb = rr2 >> 10, s = rr2 & 1023;
          if (col < 1024) {
            const int hh = col >> 6, d = col & 63;
            qb[(((size_t)(bb * NH_ + hh)) * S_ + s) * HD_ + d] = (bf16_t)(v * 0.125f);
          } else if (col < 2048) {
            const int c = col - 1024, hh = c >> 6, d = c & 63;
            kb[(((size_t)(bb * NH_ + hh)) * S_ + s) * HD_ + d] = (bf16_t)v;
          } else {
            const int c = col - 2048, hh = c >> 6, d = c & 63;
            vtb[(((size_t)(bb * NH_ + hh)) * HD_ + d) * S_ + s] = (bf16_t)v;
          }
        } else if constexpr (EPI == 2) {
          __builtin_nontemporal_store((bf16_t)fmaxf(v + bias[col], 0.0f),
                                      &bout[(size_t)rr2 * N + col]);
        } else {
          __builtin_nontemporal_store(v + bias[col], &fout[(size_t)rr2 * N + col]);
        }
      }
    }
  }
}

// ---------------------------------------------------------------------------
// m97-structure GEMM (N=1024 shapes: O-proj EPI=1, FFN2 EPI=3)
// ---------------------------------------------------------------------------
template <int EPI>
__global__ __launch_bounds__(256) void gemm_bt(
    const bf16_t* __restrict__ A, const bf16_t* __restrict__ W, int M, int N, int K,
    float* __restrict__ fout, const float* __restrict__ bias) {
  __shared__ bf16_t sA[128 * 32];
  __shared__ bf16_t sB[128 * 32];
  const int tid = threadIdx.x;
  const int wave = tid >> 6, lane = tid & 63;
  const int row16 = lane & 15, kgrp = lane >> 4;
  const int m0 = blockIdx.y * 128, n0 = blockIdx.x * 128;
  const int wr = wave >> 1, wc = wave & 1;

  const int srow  = lane >> 2;
  const int skoff = (lane & 3) * 8;
  const bf16_t* gA = A + (size_t)(m0 + wave * 32 + srow) * K + skoff;
  const bf16_t* gB = W + (size_t)(n0 + wave * 32 + srow) * K + skoff;
  bf16_t* lA0 = &sA[(wave * 2 + 0) * 512];
  bf16_t* lA1 = &sA[(wave * 2 + 1) * 512];
  bf16_t* lB0 = &sB[(wave * 2 + 0) * 512];
  bf16_t* lB1 = &sB[(wave * 2 + 1) * 512];

  f32x4 acc[4][4] = {};

  for (int k0 = 0; k0 < K; k0 += 32) {
    gload_lds16(gA + k0, lA0);
    gload_lds16(gA + k0 + (size_t)16 * K, lA1);
    gload_lds16(gB + k0, lB0);
    gload_lds16(gB + k0 + (size_t)16 * K, lB1);
    __syncthreads();
    bf16x8 af[4], bfr[4];
#pragma unroll
    for (int m = 0; m < 4; m++)
      af[m] = *(const bf16x8*)&sA[(wr * 64 + m * 16 + row16) * 32 + kgrp * 8];
#pragma unroll
    for (int n = 0; n < 4; n++)
      bfr[n] = *(const bf16x8*)&sB[(wc * 64 + n * 16 + row16) * 32 + kgrp * 8];
#pragma unroll
    for (int m = 0; m < 4; m++)
#pragma unroll
      for (int n = 0; n < 4; n++)
        acc[m][n] = MFMA_BF16(af[m], bfr[n], acc[m][n]);
    __syncthreads();
  }

#pragma unroll
  for (int m = 0; m < 4; m++) {
    const int rowb = m0 + wr * 64 + m * 16 + kgrp * 4;
#pragma unroll
    for (int n = 0; n < 4; n++) {
      const int col = n0 + wc * 64 + n * 16 + row16;
#pragma unroll
      for (int r = 0; r < 4; r++) {
        const float v = acc[m][n][r];
        const int rr = rowb + r;
        if constexpr (EPI == 1) {
          fout[(size_t)rr * N + col] += v;
        } else {
          fout[(size_t)rr * N + col] += v + bias[col];
        }
      }
    }
  }
}

// ---------------------------------------------------------------------------
// Flash attention (causal), unchanged
// ---------------------------------------------------------------------------
__global__ __launch_bounds__(256) void attn_flash(const bf16_t* __restrict__ qg,
                                                  const bf16_t* __restrict__ kg,
                                                  const bf16_t* __restrict__ vtg,
                                                  bf16_t* __restrict__ aout) {
  const int qtile = blockIdx.x;
  const int bh    = blockIdx.y;
  const int tid = threadIdx.x;
  const int wave = tid >> 6, lane = tid & 63;
  const int row16 = lane & 15, kgrp = lane >> 4;
  const int q0 = qtile * 64 + wave * 16;

  const bf16_t* qb = qg + (size_t)bh * S_ * HD_;
  const bf16_t* kb = kg + (size_t)bh * S_ * HD_;
  const bf16_t* vb = vtg + (size_t)bh * HD_ * S_;

  const bf16x8 qf0 = *(const bf16x8*)&qb[(size_t)(q0 + row16) * HD_ + kgrp * 8];
  const bf16x8 qf1 = *(const bf16x8*)&qb[(size_t)(q0 + row16) * HD_ + 32 + kgrp * 8];

  f32x4 accO[4] = {};
  float mrun[4] = {-1e30f, -1e30f, -1e30f, -1e30f};
  float lrun[4] = {0.f, 0.f, 0.f, 0.f};

  __shared__ bf16_t sP[4][16][32];

  const int kv_end = qtile * 64 + 64;
  for (int k0 = 0; k0 < kv_end; k0 += 32) {
    f32x4 sc0 = {}, sc1 = {};
    {
      bf16x8 kf0 = *(const bf16x8*)&kb[(size_t)(k0 + row16) * HD_ + kgrp * 8];
      bf16x8 kf1 = *(const bf16x8*)&kb[(size_t)(k0 + row16) * HD_ + 32 + kgrp * 8];
      sc0 = MFMA_BF16(qf0, kf0, sc0);
      sc0 = MFMA_BF16(qf1, kf1, sc0);
      bf16x8 kf2 = *(const bf16x8*)&kb[(size_t)(k0 + 16 + row16) * HD_ + kgrp * 8];
      bf16x8 kf3 = *(const bf16x8*)&kb[(size_t)(k0 + 16 + row16) * HD_ + 32 + kgrp * 8];
      sc1 = MFMA_BF16(qf0, kf2, sc1);
      sc1 = MFMA_BF16(qf1, kf3, sc1);
    }
    float p0[4], p1[4];
#pragma unroll
    for (int r = 0; r < 4; r++) {
      const int qglob = q0 + kgrp * 4 + r;
      float s0 = (k0 + row16 <= qglob) ? sc0[r] : -1e30f;
      float s1 = (k0 + 16 + row16 <= qglob) ? sc1[r] : -1e30f;
      float t = fmaxf(s0, s1);
#pragma unroll
      for (int msk = 1; msk < 16; msk <<= 1) t = fmaxf(t, __shfl_xor(t, msk, 64));
      const float mnew  = fmaxf(mrun[r], t);
      const float alpha = __expf(mrun[r] - mnew);
      const float e0 = __expf(s0 - mnew);
      const float e1 = __expf(s1 - mnew);
      float ls = e0 + e1;
#pragma unroll
      for (int msk = 1; msk < 16; msk <<= 1) ls += __shfl_xor(ls, msk, 64);
      lrun[r] = lrun[r] * alpha + ls;
      mrun[r] = mnew;
#pragma unroll
      for (int d = 0; d < 4; d++) accO[d][r] *= alpha;
      p0[r] = e0; p1[r] = e1;
    }
    __syncthreads();
#pragma unroll
    for (int r = 0; r < 4; r++) {
      sP[wave][kgrp * 4 + r][row16]      = (bf16_t)p0[r];
      sP[wave][kgrp * 4 + r][16 + row16] = (bf16_t)p1[r];
    }
    __syncthreads();
    const bf16x8 pf = *(const bf16x8*)&sP[wave][row16][kgrp * 8];
#pragma unroll
    for (int d = 0; d < 4; d++) {
      bf16x8 vf = *(const bf16x8*)&vb[(size_t)(d * 16 + row16) * S_ + k0 + kgrp * 8];
      accO[d] = MFMA_BF16(pf, vf, accO[d]);
    }
  }

  const int b = bh >> 4, hh = bh & 15;
#pragma unroll
  for (int d = 0; d < 4; d++)
#pragma unroll
    for (int r = 0; r < 4; r++) {
      const int tok = b * S_ + q0 + kgrp * 4 + r;
      aout[(size_t)tok * D_ + hh * HD_ + d * 16 + row16] = (bf16_t)(accO[d][r] / lrun[r]);
    }
}

// ---------------------------------------------------------------------------
// Launch
// ---------------------------------------------------------------------------
extern "C" void kernel_launch(void* const* d_in, const int* in_sizes, int n_in,
                              void* d_out, int out_size, void* d_ws, size_t ws_size,
                              hipStream_t stream) {
  const int*   x      = (const int*)d_in[0];
  const float* emb_W  = (const float*)d_in[1];
  const float* q_W    = (const float*)d_in[2];
  const float* k_W    = (const float*)d_in[3];
  const float* v_W    = (const float*)d_in[4];
  const float* o_W    = (const float*)d_in[5];
  const float* ln0_g  = (const float*)d_in[6];
  const float* ln0_b  = (const float*)d_in[7];
  const float* ln1_g  = (const float*)d_in[8];
  const float* ln1_b  = (const float*)d_in[9];
  const float* ffn_W1 = (const float*)d_in[10];
  const float* ffn_b1 = (const float*)d_in[11];
  const float* ffn_W2 = (const float*)d_in[12];
  const float* ffn_b2 = (const float*)d_in[13];
  const float* out_W  = (const float*)d_in[14];
  const float* out_b  = (const float*)d_in[15];
  float* out = (float*)d_out;

  char* p = (char*)d_ws;
  auto take = [&](size_t n) { char* r = p; p += (n + 255) & ~(size_t)255; return r; };
  float*  pe    = (float*)take((size_t)S_ * D_ * 4);
  float*  h     = (float*)take((size_t)TOK_ * D_ * 4);
  bf16_t* ain   = (bf16_t*)take((size_t)TOK_ * D_ * 2);
  bf16_t* attno = (bf16_t*)take((size_t)TOK_ * D_ * 2);
  bf16_t* qb    = (bf16_t*)take((size_t)B_ * NH_ * S_ * HD_ * 2);
  bf16_t* kb    = (bf16_t*)take((size_t)B_ * NH_ * S_ * HD_ * 2);
  bf16_t* vtb   = (bf16_t*)take((size_t)B_ * NH_ * S_ * HD_ * 2);
  bf16_t* ff    = (bf16_t*)take((size_t)TOK_ * HF_ * 2);
  bf16_t* qkvW  = (bf16_t*)take((size_t)3 * D_ * D_ * 2);
  bf16_t* oWb   = (bf16_t*)take((size_t)D_ * D_ * 2);
  bf16_t* W1b   = (bf16_t*)take((size_t)HF_ * D_ * 2);
  bf16_t* W2b   = (bf16_t*)take((size_t)D_ * HF_ * 2);
  bf16_t* outWb = (bf16_t*)take((size_t)V_ * D_ * 2);

  // --- weights -> bf16 ---
  cvt_f32_bf16<<<1024, 256, 0, stream>>>(q_W, qkvW, D_ * D_ / 4);
  cvt_f32_bf16<<<1024, 256, 0, stream>>>(k_W, qkvW + (size_t)D_ * D_, D_ * D_ / 4);
  cvt_f32_bf16<<<1024, 256, 0, stream>>>(v_W, qkvW + (size_t)2 * D_ * D_, D_ * D_ / 4);
  cvt_f32_bf16<<<1024, 256, 0, stream>>>(o_W, oWb, D_ * D_ / 4);
  cvt_f32_bf16<<<4096, 256, 0, stream>>>(ffn_W1, W1b, HF_ * D_ / 4);
  cvt_f32_bf16<<<4096, 256, 0, stream>>>(ffn_W2, W2b, D_ * HF_ / 4);
  cvt_f32_bf16<<<32000, 256, 0, stream>>>(out_W, outWb, V_ * D_ / 4);

  // --- embedding + PE ---
  pe_kernel<<<S_, 256, 0, stream>>>(pe);
  embed_kernel<<<TOK_ * D_ / 4 / 256, 256, 0, stream>>>(x, emb_W, pe, h);

  // --- transformer blocks (shared weights) ---
  for (int blk = 0; blk < 4; blk++) {
    ln_res_kernel<<<TOK_, 256, 0, stream>>>(h, ln0_g, ln0_b, ain);
    gemm_pipe<0><<<16 * (3 * D_ / 256), 512, 0, stream>>>(
        ain, qkvW, 3 * D_, D_, nullptr, nullptr, nullptr, qb, kb, vtb);
    attn_flash<<<dim3(S_ / 64, B_ * NH_), 256, 0, stream>>>(qb, kb, vtb, attno);
    gemm_bt<1><<<dim3(D_ / 128, TOK_ / 128), 256, 0, stream>>>(
        attno, oWb, TOK_, D_, D_, h, nullptr);
    ln_res_kernel<<<TOK_, 256, 0, stream>>>(h, ln1_g, ln1_b, ain);
    gemm_pipe<2><<<16 * (HF_ / 256), 512, 0, stream>>>(
        ain, W1b, HF_, D_, nullptr, ffn_b1, ff, nullptr, nullptr, nullptr);
    gemm_bt<3><<<dim3(D_ / 128, TOK_ / 128), 256, 0, stream>>>(
        ff, W2b, TOK_, D_, HF_, h, ffn_b2);
  }

  // --- final logits ---
  cvt_f32_bf16<<<4096, 256, 0, stream>>>(h, ain, TOK_ * D_ / 4);
  gemm_pipe<4><<<16 * (V_ / 256), 512, 0, stream>>>(
      ain, outWb, V_, D_, out, out_b, nullptr, nullptr, nullptr, nullptr);
}

// Round 5
// 1917.050 us; speedup vs baseline: 1.0587x; 1.0587x over previous
//
#include <hip/hip_runtime.h>
#include <hip/hip_bf16.h>
#include <math.h>

// ---------------------------------------------------------------------------
// Types
// ---------------------------------------------------------------------------
typedef __bf16 bf16_t;
typedef __bf16 bf16x8 __attribute__((ext_vector_type(8)));
typedef __bf16 bf16x4 __attribute__((ext_vector_type(4)));
typedef float  f32x4  __attribute__((ext_vector_type(4)));

#define MFMA_BF16(a, b, c) __builtin_amdgcn_mfma_f32_16x16x32_bf16((a), (b), (c), 0, 0, 0)

typedef const void __attribute__((address_space(1)))* gas_ptr;
typedef void       __attribute__((address_space(3)))* las_ptr;

__device__ __forceinline__ void gload_lds16(const void* g, void* l) {
  // global -> LDS direct, 16B per lane. LDS dest is wave-uniform base + lane*16.
  __builtin_amdgcn_global_load_lds((gas_ptr)g, (las_ptr)l, 16, 0, 0);
}

// ---------------------------------------------------------------------------
// Model constants
// ---------------------------------------------------------------------------
static constexpr int B_ = 4, S_ = 1024, D_ = 1024, HF_ = 4096, V_ = 32000;
static constexpr int NH_ = 16, HD_ = 64;
static constexpr int TOK_ = B_ * S_;  // 4096

// ---------------------------------------------------------------------------
// fp32 -> bf16 conversion (vectorized x4)
// ---------------------------------------------------------------------------
__global__ __launch_bounds__(256) void cvt_f32_bf16(const float* __restrict__ in,
                                                    bf16_t* __restrict__ out, int n4) {
  int i = blockIdx.x * 256 + threadIdx.x;
  if (i < n4) {
    float4 v = ((const float4*)in)[i];
    bf16x4 o;
    o[0] = (bf16_t)v.x; o[1] = (bf16_t)v.y; o[2] = (bf16_t)v.z; o[3] = (bf16_t)v.w;
    ((bf16x4*)out)[i] = o;
  }
}

// ---------------------------------------------------------------------------
// Sinusoidal positional encoding table
// ---------------------------------------------------------------------------
__global__ __launch_bounds__(256) void pe_kernel(float* __restrict__ pe) {
  const int s = blockIdx.x;
  for (int i = threadIdx.x; i < D_ / 2; i += 256) {
    float div = expf((2.0f * (float)i) * (-9.210340371976184f / (float)D_)); // ln(10000)
    float a = (float)s * div;
    pe[(size_t)s * D_ + 2 * i]     = sinf(a);
    pe[(size_t)s * D_ + 2 * i + 1] = cosf(a);
  }
}

// ---------------------------------------------------------------------------
// Embedding: h[t][d] = emb_W[x[t]][d] * 32 + pe[t % S][d]
// ---------------------------------------------------------------------------
__global__ __launch_bounds__(256) void embed_kernel(const int* __restrict__ x,
                                                    const float* __restrict__ embW,
                                                    const float* __restrict__ pe,
                                                    float* __restrict__ h) {
  int i = blockIdx.x * 256 + threadIdx.x;
  int token = i >> 8;
  int c4 = i & 255;
  int idx = x[token];
  float4 e = ((const float4*)(embW + (size_t)idx * D_))[c4];
  float4 p = ((const float4*)(pe + (size_t)(token & (S_ - 1)) * D_))[c4];
  float4 o;
  o.x = e.x * 32.0f + p.x; o.y = e.y * 32.0f + p.y;
  o.z = e.z * 32.0f + p.z; o.w = e.w * 32.0f + p.w;
  ((float4*)(h + (size_t)token * D_))[c4] = o;
}

// ---------------------------------------------------------------------------
// a_in = h + LayerNorm(h)*g + b   -> bf16
// ---------------------------------------------------------------------------
__global__ __launch_bounds__(256) void ln_res_kernel(const float* __restrict__ h,
                                                     const float* __restrict__ gamma,
                                                     const float* __restrict__ beta,
                                                     bf16_t* __restrict__ out) {
  const int row = blockIdx.x;
  const int tid = threadIdx.x;
  const float4 v = ((const float4*)(h + (size_t)row * D_))[tid];
  float s  = v.x + v.y + v.z + v.w;
  float s2 = v.x * v.x + v.y * v.y + v.z * v.z + v.w * v.w;
#pragma unroll
  for (int m = 1; m < 64; m <<= 1) {
    s  += __shfl_xor(s, m, 64);
    s2 += __shfl_xor(s2, m, 64);
  }
  __shared__ float red[2][4];
  const int wave = tid >> 6, lane = tid & 63;
  if (lane == 0) { red[0][wave] = s; red[1][wave] = s2; }
  __syncthreads();
  s  = red[0][0] + red[0][1] + red[0][2] + red[0][3];
  s2 = red[1][0] + red[1][1] + red[1][2] + red[1][3];
  const float mu   = s * (1.0f / D_);
  const float rstd = rsqrtf(s2 * (1.0f / D_) - mu * mu + 1e-5f);
  const float4 g4 = ((const float4*)gamma)[tid];
  const float4 b4 = ((const float4*)beta)[tid];
  bf16x4 o;
  o[0] = (bf16_t)(v.x + (v.x - mu) * rstd * g4.x + b4.x);
  o[1] = (bf16_t)(v.y + (v.y - mu) * rstd * g4.y + b4.y);
  o[2] = (bf16_t)(v.z + (v.z - mu) * rstd * g4.z + b4.z);
  o[3] = (bf16_t)(v.w + (v.w - mu) * rstd * g4.w + b4.w);
  ((bf16x4*)(out + (size_t)row * D_))[tid] = o;
}

// ---------------------------------------------------------------------------
// Deep-pipelined GEMM: C[4096,N] = A[4096,K] @ W[N,K]^T   (K multiple of 64)
// BM=BN=256, BK=64, 8 waves (2M x 4N), 2 LDS double-buffers (128 KB).
// 4 phases/K-tile ordered by K-half: (m0-3,k0),(m4-7,k0),(m4-7,k1),(m0-3,k1).
// Staging in quarter-units (A-khalf / B-khalf, 2 gloads each) with 6-7 phase
// lead: at tile t issue {r0: A.k1(t+1), r1: B.k0(t+2), r2: A.k0(t+2),
// r3: B.k1(t+2)} - t+2 units go into t's own buffer right after the phase
// that finishes reading the region. Waits: vmcnt(10) at r1-end (protects
// t's k1 units) and r3-end (protects t+1's k0 units); never 0 mid-loop.
// Swizzle: 64B rows, col ^ ((row>>1)&3)<<4 (0 conflicts measured r3/r4),
// applied as involution (pre-swizzled global src, linear LDS dest,
// swizzled ds_read). M-fastest block order + XCD swizzle (grid % 8 == 0).
// Epilogues: 0 QKV-scatter, 2 bias+relu->bf16, 4 bias->f32.
// ---------------------------------------------------------------------------
template <int EPI>
__global__ __launch_bounds__(512, 1) void gemm_pipe(
    const bf16_t* __restrict__ A, const bf16_t* __restrict__ W, int N, int K,
    float* __restrict__ fout, const float* __restrict__ bias, bf16_t* __restrict__ bout,
    bf16_t* __restrict__ qb, bf16_t* __restrict__ kb, bf16_t* __restrict__ vtb) {
  __shared__ char lds[2][65536];  // per buf: A [2kh][256r][64B] | B same

  const int tid = threadIdx.x;
  const int wave = tid >> 6, lane = tid & 63;
  const int row16 = lane & 15, kgrp = lane >> 4;
  const int wm = wave >> 2, wn = wave & 3;  // 2 x 4 wave grid

  // block swizzle: XCD-bijective (grid % 8 == 0), then M-fastest (16 M-tiles)
  const int nb = gridDim.x;
  const int logical = (blockIdx.x & 7) * (nb >> 3) + (blockIdx.x >> 3);
  const int m0 = (logical & 15) << 8;
  const int n0 = (logical >> 4) << 8;
  const size_t K2 = (size_t)K * 2;

  // staging: lane covers row srow, 16B at inverse-swizzled byte col in 64B row
  const int srow = tid >> 2;  // 0..127 (gload j adds 128)
  const int sw = ((tid & 3) * 16) ^ (((tid >> 3) & 3) << 4);
  const char* gA = (const char*)A + (size_t)(m0 + srow) * K2 + sw;
  const char* gB = (const char*)W + (size_t)(n0 + srow) * K2 + sw;
  char* const ldsb = &lds[0][0];
  char* const stgA = ldsb + wave * 1024;          // + lane*16 by HW
  char* const stgB = ldsb + 32768 + wave * 1024;

#define STGA(tt, kh)                                                \
  {                                                                 \
    char* d_ = stgA + (((tt) & 1) << 16) + (kh) * 16384;            \
    const char* g_ = gA + (size_t)(tt) * 128 + (kh) * 64;           \
    gload_lds16(g_, d_);                                            \
    gload_lds16(g_ + 128 * K2, d_ + 8192);                          \
  }
#define STGB(tt, kh)                                                \
  {                                                                 \
    char* d_ = stgB + (((tt) & 1) << 16) + (kh) * 16384;            \
    const char* g_ = gB + (size_t)(tt) * 128 + (kh) * 64;           \
    gload_lds16(g_, d_);                                            \
    gload_lds16(g_ + 128 * K2, d_ + 8192);                          \
  }

  // swizzled ds_read offsets
  const int colx = (kgrp * 16) ^ (((row16 >> 1) & 3) << 4);
  const int aRowB = (wm * 128 + row16) * 64 + colx;         // A region at 0
  const int bRowB = 32768 + (wn * 64 + row16) * 64 + colx;  // B region

#define LDA(mh, kh)                                                         \
  _Pragma("unroll") for (int m_ = 0; m_ < 4; m_++)                          \
      af[m_] = *(const bf16x8*)(bufp + (kh) * 16384 + aRowB +               \
                                ((mh) * 64 + m_ * 16) * 64);
#define LDB(kh)                                                             \
  _Pragma("unroll") for (int n_ = 0; n_ < 4; n_++)                          \
      bfr[n_] = *(const bf16x8*)(bufp + (kh) * 16384 + bRowB + n_ * 1024);
#define GATE()                                         \
  __builtin_amdgcn_s_barrier();                        \
  asm volatile("s_waitcnt lgkmcnt(0)" ::: "memory");   \
  __builtin_amdgcn_sched_barrier(0);
#define PMFMA(MB)                                                           \
  __builtin_amdgcn_s_setprio(1);                                            \
  _Pragma("unroll") for (int m_ = 0; m_ < 4; m_++)                          \
      _Pragma("unroll") for (int n_ = 0; n_ < 4; n_++)                      \
          acc[(MB) + m_][n_] = MFMA_BF16(af[m_], bfr[n_], acc[(MB) + m_][n_]); \
  __builtin_amdgcn_s_setprio(0);

  f32x4 acc[8][4] = {};
  const int NT = K >> 6;  // >= 2

  // prologue: prime the steady-state stage stream
  STGB(0, 0); STGA(0, 0); STGB(0, 1); STGA(0, 1);
  STGB(1, 0); STGA(1, 0); STGB(1, 1);
  asm volatile("s_waitcnt vmcnt(10)" ::: "memory");  // A.k0(0), B.k0(0) landed
  __builtin_amdgcn_s_barrier();

  for (int t = 0; t < NT; ++t) {
    const char* bufp = ldsb + ((t & 1) << 16);
    bf16x8 af[4], bfr[4];
    // ---- r0: (m0-3, k0) ----
    LDA(0, 0);
    LDB(0);
    if (t + 1 < NT) STGA(t + 1, 1);
    GATE();
    PMFMA(0);
    __builtin_amdgcn_s_barrier();
    // ---- r1: (m4-7, k0) ----
    LDA(1, 0);
    if (t + 2 < NT) STGB(t + 2, 0);
    GATE();
    PMFMA(4);
    if (t + 2 < NT)      asm volatile("s_waitcnt vmcnt(10)" ::: "memory");
    else if (t + 1 < NT) asm volatile("s_waitcnt vmcnt(8)" ::: "memory");
    else                 asm volatile("s_waitcnt vmcnt(0)" ::: "memory");
    __builtin_amdgcn_s_barrier();  // t's k1 units now visible
    // ---- r2: (m4-7, k1) ----
    LDA(1, 1);
    LDB(1);
    if (t + 2 < NT) STGA(t + 2, 0);
    GATE();
    PMFMA(4);
    __builtin_amdgcn_s_barrier();
    // ---- r3: (m0-3, k1) ----
    LDA(0, 1);
    if (t + 2 < NT) STGB(t + 2, 1);
    GATE();
    PMFMA(0);
    if (t + 1 < NT) {
      if (t + 2 < NT) asm volatile("s_waitcnt vmcnt(10)" ::: "memory");
      else            asm volatile("s_waitcnt vmcnt(4)" ::: "memory");
    }
    __builtin_amdgcn_s_barrier();  // t+1's k0 units now visible
  }
#undef STGA
#undef STGB
#undef LDA
#undef LDB
#undef GATE
#undef PMFMA

  // epilogue: C row = m0+wm*128+m*16+kgrp*4+r, col = n0+wn*64+n*16+row16
#pragma unroll
  for (int m = 0; m < 8; m++) {
    const int rowb = m0 + wm * 128 + m * 16 + kgrp * 4;
#pragma unroll
    for (int n = 0; n < 4; n++) {
      const int col = n0 + wn * 64 + n * 16 + row16;
#pragma unroll
      for (int r = 0; r < 4; r++) {
        const float v = acc[m][n][r];
        const int rr2 = rowb + r;
        if constexpr (EPI == 0) {
          const int bb = rr2 >> 10, s = rr2 & 1023;
          if (col < 1024) {
            const int hh = col >> 6, d = col & 63;
            qb[(((size_t)(bb * NH_ + hh)) * S_ + s) * HD_ + d] = (bf16_t)(v * 0.125f);
          } else if (col < 2048) {
            const int c = col - 1024, hh = c >> 6, d = c & 63;
            kb[(((size_t)(bb * NH_ + hh)) * S_ + s) * HD_ + d] = (bf16_t)v;
          } else {
            const int c = col - 2048, hh = c >> 6, d = c & 63;
            vtb[(((size_t)(bb * NH_ + hh)) * HD_ + d) * S_ + s] = (bf16_t)v;
          }
        } else if constexpr (EPI == 2) {
          bout[(size_t)rr2 * N + col] = (bf16_t)fmaxf(v + bias[col], 0.0f);
        } else {
          fout[(size_t)rr2 * N + col] = v + bias[col];
        }
      }
    }
  }
}

// ---------------------------------------------------------------------------
// m97-structure GEMM (N=1024 shapes: O-proj EPI=1, FFN2 EPI=3)
// ---------------------------------------------------------------------------
template <int EPI>
__global__ __launch_bounds__(256) void gemm_bt(
    const bf16_t* __restrict__ A, const bf16_t* __restrict__ W, int M, int N, int K,
    float* __restrict__ fout, const float* __restrict__ bias) {
  __shared__ bf16_t sA[128 * 32];
  __shared__ bf16_t sB[128 * 32];
  const int tid = threadIdx.x;
  const int wave = tid >> 6, lane = tid & 63;
  const int row16 = lane & 15, kgrp = lane >> 4;
  const int m0 = blockIdx.y * 128, n0 = blockIdx.x * 128;
  const int wr = wave >> 1, wc = wave & 1;

  const int srow  = lane >> 2;
  const int skoff = (lane & 3) * 8;
  const bf16_t* gA = A + (size_t)(m0 + wave * 32 + srow) * K + skoff;
  const bf16_t* gB = W + (size_t)(n0 + wave * 32 + srow) * K + skoff;
  bf16_t* lA0 = &sA[(wave * 2 + 0) * 512];
  bf16_t* lA1 = &sA[(wave * 2 + 1) * 512];
  bf16_t* lB0 = &sB[(wave * 2 + 0) * 512];
  bf16_t* lB1 = &sB[(wave * 2 + 1) * 512];

  f32x4 acc[4][4] = {};

  for (int k0 = 0; k0 < K; k0 += 32) {
    gload_lds16(gA + k0, lA0);
    gload_lds16(gA + k0 + (size_t)16 * K, lA1);
    gload_lds16(gB + k0, lB0);
    gload_lds16(gB + k0 + (size_t)16 * K, lB1);
    __syncthreads();
    bf16x8 af[4], bfr[4];
#pragma unroll
    for (int m = 0; m < 4; m++)
      af[m] = *(const bf16x8*)&sA[(wr * 64 + m * 16 + row16) * 32 + kgrp * 8];
#pragma unroll
    for (int n = 0; n < 4; n++)
      bfr[n] = *(const bf16x8*)&sB[(wc * 64 + n * 16 + row16) * 32 + kgrp * 8];
#pragma unroll
    for (int m = 0; m < 4; m++)
#pragma unroll
      for (int n = 0; n < 4; n++)
        acc[m][n] = MFMA_BF16(af[m], bfr[n], acc[m][n]);
    __syncthreads();
  }

#pragma unroll
  for (int m = 0; m < 4; m++) {
    const int rowb = m0 + wr * 64 + m * 16 + kgrp * 4;
#pragma unroll
    for (int n = 0; n < 4; n++) {
      const int col = n0 + wc * 64 + n * 16 + row16;
#pragma unroll
      for (int r = 0; r < 4; r++) {
        const float v = acc[m][n][r];
        const int rr = rowb + r;
        if constexpr (EPI == 1) {
          fout[(size_t)rr * N + col] += v;
        } else {
          fout[(size_t)rr * N + col] += v + bias[col];
        }
      }
    }
  }
}

// ---------------------------------------------------------------------------
// Flash attention (causal), unchanged
// ---------------------------------------------------------------------------
__global__ __launch_bounds__(256) void attn_flash(const bf16_t* __restrict__ qg,
                                                  const bf16_t* __restrict__ kg,
                                                  const bf16_t* __restrict__ vtg,
                                                  bf16_t* __restrict__ aout) {
  const int qtile = blockIdx.x;
  const int bh    = blockIdx.y;
  const int tid = threadIdx.x;
  const int wave = tid >> 6, lane = tid & 63;
  const int row16 = lane & 15, kgrp = lane >> 4;
  const int q0 = qtile * 64 + wave * 16;

  const bf16_t* qb = qg + (size_t)bh * S_ * HD_;
  const bf16_t* kb = kg + (size_t)bh * S_ * HD_;
  const bf16_t* vb = vtg + (size_t)bh * HD_ * S_;

  const bf16x8 qf0 = *(const bf16x8*)&qb[(size_t)(q0 + row16) * HD_ + kgrp * 8];
  const bf16x8 qf1 = *(const bf16x8*)&qb[(size_t)(q0 + row16) * HD_ + 32 + kgrp * 8];

  f32x4 accO[4] = {};
  float mrun[4] = {-1e30f, -1e30f, -1e30f, -1e30f};
  float lrun[4] = {0.f, 0.f, 0.f, 0.f};

  __shared__ bf16_t sP[4][16][32];

  const int kv_end = qtile * 64 + 64;
  for (int k0 = 0; k0 < kv_end; k0 += 32) {
    f32x4 sc0 = {}, sc1 = {};
    {
      bf16x8 kf0 = *(const bf16x8*)&kb[(size_t)(k0 + row16) * HD_ + kgrp * 8];
      bf16x8 kf1 = *(const bf16x8*)&kb[(size_t)(k0 + row16) * HD_ + 32 + kgrp * 8];
      sc0 = MFMA_BF16(qf0, kf0, sc0);
      sc0 = MFMA_BF16(qf1, kf1, sc0);
      bf16x8 kf2 = *(const bf16x8*)&kb[(size_t)(k0 + 16 + row16) * HD_ + kgrp * 8];
      bf16x8 kf3 = *(const bf16x8*)&kb[(size_t)(k0 + 16 + row16) * HD_ + 32 + kgrp * 8];
      sc1 = MFMA_BF16(qf0, kf2, sc1);
      sc1 = MFMA_BF16(qf1, kf3, sc1);
    }
    float p0[4], p1[4];
#pragma unroll
    for (int r = 0; r < 4; r++) {
      const int qglob = q0 + kgrp * 4 + r;
      float s0 = (k0 + row16 <= qglob) ? sc0[r] : -1e30f;
      float s1 = (k0 + 16 + row16 <= qglob) ? sc1[r] : -1e30f;
      float t = fmaxf(s0, s1);
#pragma unroll
      for (int msk = 1; msk < 16; msk <<= 1) t = fmaxf(t, __shfl_xor(t, msk, 64));
      const float mnew  = fmaxf(mrun[r], t);
      const float alpha = __expf(mrun[r] - mnew);
      const float e0 = __expf(s0 - mnew);
      const float e1 = __expf(s1 - mnew);
      float ls = e0 + e1;
#pragma unroll
      for (int msk = 1; msk < 16; msk <<= 1) ls += __shfl_xor(ls, msk, 64);
      lrun[r] = lrun[r] * alpha + ls;
      mrun[r] = mnew;
#pragma unroll
      for (int d = 0; d < 4; d++) accO[d][r] *= alpha;
      p0[r] = e0; p1[r] = e1;
    }
    __syncthreads();
#pragma unroll
    for (int r = 0; r < 4; r++) {
      sP[wave][kgrp * 4 + r][row16]      = (bf16_t)p0[r];
      sP[wave][kgrp * 4 + r][16 + row16] = (bf16_t)p1[r];
    }
    __syncthreads();
    const bf16x8 pf = *(const bf16x8*)&sP[wave][row16][kgrp * 8];
#pragma unroll
    for (int d = 0; d < 4; d++) {
      bf16x8 vf = *(const bf16x8*)&vb[(size_t)(d * 16 + row16) * S_ + k0 + kgrp * 8];
      accO[d] = MFMA_BF16(pf, vf, accO[d]);
    }
  }

  const int b = bh >> 4, hh = bh & 15;
#pragma unroll
  for (int d = 0; d < 4; d++)
#pragma unroll
    for (int r = 0; r < 4; r++) {
      const int tok = b * S_ + q0 + kgrp * 4 + r;
      aout[(size_t)tok * D_ + hh * HD_ + d * 16 + row16] = (bf16_t)(accO[d][r] / lrun[r]);
    }
}

// ---------------------------------------------------------------------------
// Launch
// ---------------------------------------------------------------------------
extern "C" void kernel_launch(void* const* d_in, const int* in_sizes, int n_in,
                              void* d_out, int out_size, void* d_ws, size_t ws_size,
                              hipStream_t stream) {
  const int*   x      = (const int*)d_in[0];
  const float* emb_W  = (const float*)d_in[1];
  const float* q_W    = (const float*)d_in[2];
  const float* k_W    = (const float*)d_in[3];
  const float* v_W    = (const float*)d_in[4];
  const float* o_W    = (const float*)d_in[5];
  const float* ln0_g  = (const float*)d_in[6];
  const float* ln0_b  = (const float*)d_in[7];
  const float* ln1_g  = (const float*)d_in[8];
  const float* ln1_b  = (const float*)d_in[9];
  const float* ffn_W1 = (const float*)d_in[10];
  const float* ffn_b1 = (const float*)d_in[11];
  const float* ffn_W2 = (const float*)d_in[12];
  const float* ffn_b2 = (const float*)d_in[13];
  const float* out_W  = (const float*)d_in[14];
  const float* out_b  = (const float*)d_in[15];
  float* out = (float*)d_out;

  char* p = (char*)d_ws;
  auto take = [&](size_t n) { char* r = p; p += (n + 255) & ~(size_t)255; return r; };
  float*  pe    = (float*)take((size_t)S_ * D_ * 4);
  float*  h     = (float*)take((size_t)TOK_ * D_ * 4);
  bf16_t* ain   = (bf16_t*)take((size_t)TOK_ * D_ * 2);
  bf16_t* attno = (bf16_t*)take((size_t)TOK_ * D_ * 2);
  bf16_t* qb    = (bf16_t*)take((size_t)B_ * NH_ * S_ * HD_ * 2);
  bf16_t* kb    = (bf16_t*)take((size_t)B_ * NH_ * S_ * HD_ * 2);
  bf16_t* vtb   = (bf16_t*)take((size_t)B_ * NH_ * S_ * HD_ * 2);
  bf16_t* ff    = (bf16_t*)take((size_t)TOK_ * HF_ * 2);
  bf16_t* qkvW  = (bf16_t*)take((size_t)3 * D_ * D_ * 2);
  bf16_t* oWb   = (bf16_t*)take((size_t)D_ * D_ * 2);
  bf16_t* W1b   = (bf16_t*)take((size_t)HF_ * D_ * 2);
  bf16_t* W2b   = (bf16_t*)take((size_t)D_ * HF_ * 2);
  bf16_t* outWb = (bf16_t*)take((size_t)V_ * D_ * 2);

  // --- weights -> bf16 ---
  cvt_f32_bf16<<<1024, 256, 0, stream>>>(q_W, qkvW, D_ * D_ / 4);
  cvt_f32_bf16<<<1024, 256, 0, stream>>>(k_W, qkvW + (size_t)D_ * D_, D_ * D_ / 4);
  cvt_f32_bf16<<<1024, 256, 0, stream>>>(v_W, qkvW + (size_t)2 * D_ * D_, D_ * D_ / 4);
  cvt_f32_bf16<<<1024, 256, 0, stream>>>(o_W, oWb, D_ * D_ / 4);
  cvt_f32_bf16<<<4096, 256, 0, stream>>>(ffn_W1, W1b, HF_ * D_ / 4);
  cvt_f32_bf16<<<4096, 256, 0, stream>>>(ffn_W2, W2b, D_ * HF_ / 4);
  cvt_f32_bf16<<<32000, 256, 0, stream>>>(out_W, outWb, V_ * D_ / 4);

  // --- embedding + PE ---
  pe_kernel<<<S_, 256, 0, stream>>>(pe);
  embed_kernel<<<TOK_ * D_ / 4 / 256, 256, 0, stream>>>(x, emb_W, pe, h);

  // --- transformer blocks (shared weights) ---
  for (int blk = 0; blk < 4; blk++) {
    ln_res_kernel<<<TOK_, 256, 0, stream>>>(h, ln0_g, ln0_b, ain);
    gemm_pipe<0><<<16 * (3 * D_ / 256), 512, 0, stream>>>(
        ain, qkvW, 3 * D_, D_, nullptr, nullptr, nullptr, qb, kb, vtb);
    attn_flash<<<dim3(S_ / 64, B_ * NH_), 256, 0, stream>>>(qb, kb, vtb, attno);
    gemm_bt<1><<<dim3(D_ / 128, TOK_ / 128), 256, 0, stream>>>(
        attno, oWb, TOK_, D_, D_, h, nullptr);
    ln_res_kernel<<<TOK_, 256, 0, stream>>>(h, ln1_g, ln1_b, ain);
    gemm_pipe<2><<<16 * (HF_ / 256), 512, 0, stream>>>(
        ain, W1b, HF_, D_, nullptr, ffn_b1, ff, nullptr, nullptr, nullptr);
    gemm_bt<3><<<dim3(D_ / 128, TOK_ / 128), 256, 0, stream>>>(
        ff, W2b, TOK_, D_, HF_, h, ffn_b2);
  }

  // --- final logits ---
  cvt_f32_bf16<<<4096, 256, 0, stream>>>(h, ain, TOK_ * D_ / 4);
  gemm_pipe<4><<<16 * (V_ / 256), 512, 0, stream>>>(
      ain, outWb, V_, D_, out, out_b, nullptr, nullptr, nullptr, nullptr);
}